// Round 2
// 664.788 us; speedup vs baseline: 1.0184x; 1.0184x over previous
//
#include <hip/hip_runtime.h>
#include <hip/hip_bf16.h>
#include <cstdint>
#include <cstddef>

#define N_NODES   100000
#define N_EDGES   3200000
#define IN_FEATS  256
#define N_HIDDEN  128
#define OUT_FEATS 40
#define H1_PITCH  64       // h1 row padded to 64 bf16 = 128 B (2 aligned lines)

// Bucket partition: bucket = dst >> 9 (512 nodes/bucket)
#define NB        196
#define EPB       8192
#define NBLK      391
#define HIST_M    (NB * NBLK)

typedef __attribute__((ext_vector_type(8))) __bf16 bf16x8;
typedef __attribute__((ext_vector_type(4))) float f32x4;

// unpack a uint4 holding 8 bf16 (low short = even feature) and fma all 8.
// NOTE: macro params named V_/W_ so they cannot collide with .x/.y/.z/.w
// member accesses (previous round's compile failure).
#define ACC8(V_, W_)                                                     \
  acc[0] = fmaf(__uint_as_float((V_).x << 16),         (W_), acc[0]);    \
  acc[1] = fmaf(__uint_as_float((V_).x & 0xFFFF0000u), (W_), acc[1]);    \
  acc[2] = fmaf(__uint_as_float((V_).y << 16),         (W_), acc[2]);    \
  acc[3] = fmaf(__uint_as_float((V_).y & 0xFFFF0000u), (W_), acc[3]);    \
  acc[4] = fmaf(__uint_as_float((V_).z << 16),         (W_), acc[4]);    \
  acc[5] = fmaf(__uint_as_float((V_).z & 0xFFFF0000u), (W_), acc[5]);    \
  acc[6] = fmaf(__uint_as_float((V_).w << 16),         (W_), acc[6]);    \
  acc[7] = fmaf(__uint_as_float((V_).w & 0xFFFF0000u), (W_), acc[7]);

// ---------------------------------------------------------------------------
// GEMM0 block body (MFMA): h0 = bf16(bf16(x) @ bf16(W0)), 32 rows x 128 cols
// per block, 5 tiles/block. Called from the combo kernel below.
// ---------------------------------------------------------------------------
__device__ __forceinline__ void gemm0_block(
    int bid, const float* __restrict__ x, const float* __restrict__ W0,
    unsigned short* __restrict__ h0) {
  __shared__ __align__(16) unsigned short xb[32 * 264];
  const int tid  = threadIdx.x;
  const int lane = tid & 63;
  const int wave = tid >> 6;
  const int rb   = wave & 1;
  const int ch   = wave >> 1;
  const int l15  = lane & 15;
  const int g    = lane >> 4;

  bf16x8 Bf[4][8];
#pragma unroll
  for (int cb = 0; cb < 4; ++cb) {
    const int col = ch * 64 + cb * 16 + l15;
#pragma unroll
    for (int q = 0; q < 8; ++q) {
      const int k0 = q * 32 + g * 8;
      uint4 uw;
      {
        __hip_bfloat162 p;
        p.x = __float2bfloat16(W0[(size_t)(k0 + 0) * N_HIDDEN + col]);
        p.y = __float2bfloat16(W0[(size_t)(k0 + 1) * N_HIDDEN + col]);
        uw.x = *(unsigned int*)&p;
        p.x = __float2bfloat16(W0[(size_t)(k0 + 2) * N_HIDDEN + col]);
        p.y = __float2bfloat16(W0[(size_t)(k0 + 3) * N_HIDDEN + col]);
        uw.y = *(unsigned int*)&p;
        p.x = __float2bfloat16(W0[(size_t)(k0 + 4) * N_HIDDEN + col]);
        p.y = __float2bfloat16(W0[(size_t)(k0 + 5) * N_HIDDEN + col]);
        uw.z = *(unsigned int*)&p;
        p.x = __float2bfloat16(W0[(size_t)(k0 + 6) * N_HIDDEN + col]);
        p.y = __float2bfloat16(W0[(size_t)(k0 + 7) * N_HIDDEN + col]);
        uw.w = *(unsigned int*)&p;
      }
      Bf[cb][q] = __builtin_bit_cast(bf16x8, uw);
    }
  }

  for (int t = 0; t < 5; ++t) {
    const int row0 = (bid * 5 + t) * 32;
    __syncthreads();
    for (int i = tid; i < 32 * 128; i += 256) {
      const int row = i >> 7, kp = i & 127;
      const float2 v = *(const float2*)(x + (size_t)(row0 + row) * IN_FEATS + kp * 2);
      __hip_bfloat162 p;
      p.x = __float2bfloat16(v.x);
      p.y = __float2bfloat16(v.y);
      *(unsigned int*)&xb[row * 264 + kp * 2] = *(unsigned int*)&p;
    }
    __syncthreads();

    f32x4 acc[4];
#pragma unroll
    for (int cb = 0; cb < 4; ++cb) acc[cb] = (f32x4){0.f, 0.f, 0.f, 0.f};

#pragma unroll
    for (int q = 0; q < 8; ++q) {
      const bf16x8 a = *(const bf16x8*)&xb[(rb * 16 + l15) * 264 + q * 32 + g * 8];
      acc[0] = __builtin_amdgcn_mfma_f32_16x16x32_bf16(a, Bf[0][q], acc[0], 0, 0, 0);
      acc[1] = __builtin_amdgcn_mfma_f32_16x16x32_bf16(a, Bf[1][q], acc[1], 0, 0, 0);
      acc[2] = __builtin_amdgcn_mfma_f32_16x16x32_bf16(a, Bf[2][q], acc[2], 0, 0, 0);
      acc[3] = __builtin_amdgcn_mfma_f32_16x16x32_bf16(a, Bf[3][q], acc[3], 0, 0, 0);
    }

#pragma unroll
    for (int cb = 0; cb < 4; ++cb) {
      const int col = ch * 64 + cb * 16 + l15;
#pragma unroll
      for (int r = 0; r < 4; ++r) {
        const int row = row0 + rb * 16 + g * 4 + r;
        __hip_bfloat16 hb = __float2bfloat16(acc[cb][r]);
        h0[(size_t)row * N_HIDDEN + col] = *(unsigned short*)&hb;
      }
    }
  }
}

// ---------------------------------------------------------------------------
// 256-thread exclusive scan of histG (block 0 of the combo dispatch).
// ---------------------------------------------------------------------------
__device__ __forceinline__ void gscan256_block(int* __restrict__ histG) {
  __shared__ int partials[256];
  const int t = threadIdx.x;
  const int chunk = (HIST_M + 255) / 256;   // 300
  const int lo = t * chunk;
  const int hi = min(lo + chunk, HIST_M);

  int sum = 0;
  for (int i = lo; i < hi; ++i) sum += histG[i];
  partials[t] = sum;
  __syncthreads();

  for (int off = 1; off < 256; off <<= 1) {
    int v = (t >= off) ? partials[t - off] : 0;
    __syncthreads();
    partials[t] += v;
    __syncthreads();
  }

  int run = (t > 0) ? partials[t - 1] : 0;
  for (int i = lo; i < hi; ++i) {
    const int d = histG[i];
    histG[i] = run;
    run += d;
  }
}

// Combo: block 0 runs the scan (1-block serialization hidden under gemm work),
// blocks 1..625 run gemm0. gemm0 depends only on x/W0; scan only on histG.
__global__ __launch_bounds__(256) void gscan_gemm0_kernel(
    int* __restrict__ histG, const float* __restrict__ x,
    const float* __restrict__ W0, unsigned short* __restrict__ h0) {
  if (blockIdx.x == 0) gscan256_block(histG);
  else                 gemm0_block(blockIdx.x - 1, x, W0, h0);
}

// ---------------------------------------------------------------------------
// CSR build: p1hist -> (gscan in combo) -> p1scatter -> p2place.
// ---------------------------------------------------------------------------
__global__ __launch_bounds__(256) void p1hist_kernel(
    const int* __restrict__ dst, int* __restrict__ histG) {
  __shared__ int lh[NB];
  const int tid = threadIdx.x;
  const int blk = blockIdx.x;
  for (int i = tid; i < NB; i += 256) lh[i] = 0;
  __syncthreads();

  const int e0 = blk * EPB;
  const int e1 = min(e0 + EPB, N_EDGES);
  for (int i = e0 + tid; i < e1; i += 256)
    atomicAdd(&lh[dst[i] >> 9], 1);
  __syncthreads();

  for (int i = tid; i < NB; i += 256)
    histG[i * NBLK + blk] = lh[i];
}

__global__ __launch_bounds__(256) void p1scatter_kernel(
    const int* __restrict__ src, const int* __restrict__ dst,
    const float* __restrict__ ew, const int* __restrict__ histG,
    uint2* __restrict__ bucketed) {
  __shared__ int cur[NB];
  const int tid = threadIdx.x;
  const int blk = blockIdx.x;
  for (int i = tid; i < NB; i += 256) cur[i] = histG[i * NBLK + blk];
  __syncthreads();

  const int e0 = blk * EPB;
  const int e1 = min(e0 + EPB, N_EDGES);
  for (int i = e0 + tid; i < e1; i += 256) {
    const int d = dst[i];
    const int b = d >> 9;
    const int pos = atomicAdd(&cur[b], 1);
    bucketed[pos] = make_uint2((unsigned)src[i] | ((unsigned)(d & 511) << 17),
                               __float_as_uint(ew[i]));
  }
}

__global__ __launch_bounds__(256) void p2place_kernel(
    const uint2* __restrict__ bucketed, const int* __restrict__ histG,
    int* __restrict__ offsets, int2* __restrict__ srcw) {
  __shared__ int cnt[512];
  __shared__ int part[256];
  const int t = threadIdx.x;
  const int b = blockIdx.x;
  const int node0 = b << 9;
  const int beg = histG[b * NBLK];
  const int end = (b == NB - 1) ? N_EDGES : histG[(b + 1) * NBLK];

  cnt[t] = 0; cnt[t + 256] = 0;
  __syncthreads();

  for (int j = beg + t; j < end; j += 256)
    atomicAdd(&cnt[bucketed[j].x >> 17], 1);
  __syncthreads();

  const int a0 = cnt[2 * t];
  const int a1 = cnt[2 * t + 1];
  part[t] = a0 + a1;
  __syncthreads();
  for (int off = 1; off < 256; off <<= 1) {
    int v = (t >= off) ? part[t - off] : 0;
    __syncthreads();
    part[t] += v;
    __syncthreads();
  }
  const int base = (t > 0) ? part[t - 1] : 0;

  const int o0 = beg + base;
  const int o1 = o0 + a0;
  cnt[2 * t]     = o0;
  cnt[2 * t + 1] = o1;
  const int n0 = node0 + 2 * t;
  if (n0 < N_NODES)     offsets[n0]     = o0;
  if (n0 + 1 < N_NODES) offsets[n0 + 1] = o1;
  if (b == NB - 1 && t == 0) offsets[N_NODES] = N_EDGES;
  __syncthreads();

  for (int j = beg + t; j < end; j += 256) {
    const uint2 en = bucketed[j];
    const int slot = atomicAdd(&cnt[en.x >> 17], 1);
    srcw[slot] = make_int2((int)(en.x & 0x1FFFFu), (int)en.y);
  }
}

// ---------------------------------------------------------------------------
// Fused gather0 + bias + ReLU + GEMM1.
// Layout: 16 lanes per edge, dwordx4 gathers -> 4 edges per load instr,
// 2 edge-groups unrolled (16 edges in flight/wave), srcw meta prefetched one
// iteration ahead. Tail edges handled by clamped index + zero weight.
// ---------------------------------------------------------------------------
__global__ __launch_bounds__(256) void gather0_gemm1_kernel(
    const uint4* __restrict__ h0q, const int2* __restrict__ srcw,
    const int* __restrict__ offsets, const float* __restrict__ b0,
    const float* __restrict__ W1, unsigned short* __restrict__ h1b) {
  __shared__ float hs[4][N_HIDDEN];
  const int wave = threadIdx.x >> 6;
  const int lane = threadIdx.x & 63;
  const int node = blockIdx.x * 4 + wave;
  const int q    = lane >> 4;       // edge slot 0..3 within a 4-edge group
  const int fl   = lane & 15;       // feature chunk: feats [fl*8, fl*8+8)

  const int beg = __builtin_amdgcn_readfirstlane(offsets[node]);
  const int end = __builtin_amdgcn_readfirstlane(offsets[node + 1]);

  float acc[8] = {0.f, 0.f, 0.f, 0.f, 0.f, 0.f, 0.f, 0.f};

  if (end > beg) {
    const int e1 = end - 1;
    int2 sA = srcw[min(beg + q, e1)];
    int2 sB = srcw[min(beg + 4 + q, e1)];
    for (int j = beg; j < end; j += 8) {
      const float wA = (j + q < end)     ? __int_as_float(sA.y) : 0.f;
      const float wB = (j + 4 + q < end) ? __int_as_float(sB.y) : 0.f;
      const uint4 vA = h0q[(size_t)(unsigned)sA.x * 16 + fl];
      const uint4 vB = h0q[(size_t)(unsigned)sB.x * 16 + fl];
      const int jn = j + 8;
      if (jn < end) {                 // prefetch next groups' meta
        sA = srcw[min(jn + q, e1)];
        sB = srcw[min(jn + 4 + q, e1)];
      }
      ACC8(vA, wA)
      ACC8(vB, wB)
    }
  }

  // reduce the 4 edge-groups (lanes xor 16, 32 hold same features)
#pragma unroll
  for (int i = 0; i < 8; ++i) {
    acc[i] += __shfl_xor(acc[i], 16);
    acc[i] += __shfl_xor(acc[i], 32);
  }

  // bias + ReLU, one quarter-wave writes the 128-float row to LDS
  if (q == 0) {
    const int f0 = fl * 8;
    float t[8];
#pragma unroll
    for (int i = 0; i < 8; ++i) {
      const float v = acc[i] + b0[f0 + i];
      t[i] = v > 0.f ? v : 0.f;
    }
    *(float4*)&hs[wave][f0]     = make_float4(t[0], t[1], t[2], t[3]);
    *(float4*)&hs[wave][f0 + 4] = make_float4(t[4], t[5], t[6], t[7]);
  }
  __syncthreads();

  unsigned short w16 = 0;
  if (lane < OUT_FEATS) {
    float o = 0.f;
#pragma unroll 8
    for (int k = 0; k < N_HIDDEN; ++k)
      o = fmaf(hs[wave][k], W1[k * OUT_FEATS + lane], o);
    __hip_bfloat16 hb = __float2bfloat16(o);
    w16 = *(unsigned short*)&hb;
  }
  h1b[(size_t)node * H1_PITCH + lane] = w16;   // pad lanes write 0: full lines
}

// ---------------------------------------------------------------------------
// Fused gather1 + bias + log_softmax.
// Layout: 8 lanes per edge, dwordx4 gathers -> 8 edges per load instr
// (was 40x 2-byte loads/edge with 24 idle lanes), 2 groups unrolled.
// ---------------------------------------------------------------------------
__global__ __launch_bounds__(256) void gather1_lsm_kernel(
    const uint4* __restrict__ h1q, const int2* __restrict__ srcw,
    const int* __restrict__ offsets, const float* __restrict__ b1,
    float* __restrict__ out) {
  const int wave = threadIdx.x >> 6;
  const int lane = threadIdx.x & 63;
  const int node = blockIdx.x * 4 + wave;
  const int g  = lane >> 3;         // edge slot 0..7 within an 8-edge group
  const int fl = lane & 7;          // feats [fl*8, fl*8+8) of the 64-pitch row

  const int beg = __builtin_amdgcn_readfirstlane(offsets[node]);
  const int end = __builtin_amdgcn_readfirstlane(offsets[node + 1]);

  float acc[8] = {0.f, 0.f, 0.f, 0.f, 0.f, 0.f, 0.f, 0.f};

  if (end > beg) {
    const int e1 = end - 1;
    int2 sA = srcw[min(beg + g, e1)];
    int2 sB = srcw[min(beg + 8 + g, e1)];
    for (int j = beg; j < end; j += 16) {
      const float wA = (j + g < end)     ? __int_as_float(sA.y) : 0.f;
      const float wB = (j + 8 + g < end) ? __int_as_float(sB.y) : 0.f;
      const uint4 vA = h1q[(size_t)(unsigned)sA.x * 8 + fl];
      const uint4 vB = h1q[(size_t)(unsigned)sB.x * 8 + fl];
      const int jn = j + 16;
      if (jn < end) {
        sA = srcw[min(jn + g, e1)];
        sB = srcw[min(jn + 8 + g, e1)];
      }
      ACC8(vA, wA)
      ACC8(vB, wB)
    }
  }

  // reduce the 8 edge-groups
#pragma unroll
  for (int i = 0; i < 8; ++i) {
    acc[i] += __shfl_xor(acc[i], 8);
    acc[i] += __shfl_xor(acc[i], 16);
    acc[i] += __shfl_xor(acc[i], 32);
  }

  const bool valid = (fl < 5);      // feats fl*8..fl*8+7 < 40
  float m = -INFINITY;
  if (valid) {
    const int f0 = fl * 8;
#pragma unroll
    for (int i = 0; i < 8; ++i) acc[i] += b1[f0 + i];
#pragma unroll
    for (int i = 0; i < 8; ++i) m = fmaxf(m, acc[i]);
  }
#pragma unroll
  for (int off = 1; off < 8; off <<= 1) m = fmaxf(m, __shfl_xor(m, off));

  float ssum = 0.f;
  if (valid) {
#pragma unroll
    for (int i = 0; i < 8; ++i) ssum += expf(acc[i] - m);
  }
#pragma unroll
  for (int off = 1; off < 8; off <<= 1) ssum += __shfl_xor(ssum, off);

  if (lane < 5) {                   // g==0 && fl<5: write all 40 outputs
    const float lse = m + logf(ssum);
    float* op = out + (size_t)node * OUT_FEATS + fl * 8;
    *(float4*)op       = make_float4(acc[0] - lse, acc[1] - lse,
                                     acc[2] - lse, acc[3] - lse);
    *(float4*)(op + 4) = make_float4(acc[4] - lse, acc[5] - lse,
                                     acc[6] - lse, acc[7] - lse);
  }
}

// ---------------------------------------------------------------------------
extern "C" void kernel_launch(void* const* d_in, const int* in_sizes, int n_in,
                              void* d_out, int out_size, void* d_ws, size_t ws_size,
                              hipStream_t stream) {
  const float* x   = (const float*)d_in[0];
  const float* W0  = (const float*)d_in[1];
  const float* b0  = (const float*)d_in[2];
  const float* W1  = (const float*)d_in[3];
  const float* b1  = (const float*)d_in[4];
  const float* ew  = (const float*)d_in[5];
  const int*   src = (const int*)d_in[6];
  const int*   dst = (const int*)d_in[7];
  float* out = (float*)d_out;

  // Workspace layout, peak ~90.3 MB (ws >= 102.4 MB proven in R1):
  //   h0b2     [0,          25,600,000)   N*128 bf16
  //   srcw     [25,600,000, 51,200,000)   E int2, dst-sorted
  //   bucketed [51,200,000, 76,800,000)   E uint2, bucket-partitioned
  //   offsets  [76,800,000, 77,200,064)   N+1 int
  //   histG    [77,200,064, 77,506,624)   NB*NBLK int
  //   h1b      [77,506,624, 90,306,624)   N*64 bf16 (pitch-64, 128B rows)
  char* ws = (char*)d_ws;
  unsigned int* h0b2 = (unsigned int*)(ws);
  int2*  srcw     = (int2*)(ws + 25600000);
  uint2* bucketed = (uint2*)(ws + 51200000);
  int*   offsets  = (int*)(ws + 76800000);
  int*   histG    = (int*)(ws + 77200064);
  unsigned short* h1b = (unsigned short*)(ws + 77506624);

  p1hist_kernel<<<NBLK, 256, 0, stream>>>(dst, histG);
  // gscan (block 0) hidden under gemm0 (blocks 1..625) in one dispatch.
  gscan_gemm0_kernel<<<626, 256, 0, stream>>>(histG, x, W0, (unsigned short*)h0b2);
  p1scatter_kernel<<<NBLK, 256, 0, stream>>>(src, dst, ew, histG, bucketed);
  p2place_kernel<<<NB, 256, 0, stream>>>(bucketed, histG, offsets, srcw);

  gather0_gemm1_kernel<<<N_NODES / 4, 256, 0, stream>>>(
      (const uint4*)h0b2, srcw, offsets, b0, W1, h1b);
  gather1_lsm_kernel<<<N_NODES / 4, 256, 0, stream>>>(
      (const uint4*)h1b, srcw, offsets, b1, out);
}

// Round 3
// 619.443 us; speedup vs baseline: 1.0930x; 1.0732x over previous
//
#include <hip/hip_runtime.h>
#include <hip/hip_bf16.h>
#include <cstdint>
#include <cstddef>

#define N_NODES   100000
#define N_EDGES   3200000
#define IN_FEATS  256
#define N_HIDDEN  128
#define OUT_FEATS 40

// Bucket partition: bucket = dst >> 9 (512 nodes/bucket)
#define NB        196
#define EPB       8192
#define NBLK      391
#define HIST_M    (NB * NBLK)

typedef __attribute__((ext_vector_type(8))) __bf16 bf16x8;
typedef __attribute__((ext_vector_type(4))) float f32x4;

// unpack a uint4 holding 8 bf16 (low short = even feature) and fma all 8
// into array A_. Params named V_/W_ to avoid .x/.y/.z/.w collision.
#define ACC8(A_, V_, W_)                                                  \
  A_[0] = fmaf(__uint_as_float((V_).x << 16),         (W_), A_[0]);       \
  A_[1] = fmaf(__uint_as_float((V_).x & 0xFFFF0000u), (W_), A_[1]);       \
  A_[2] = fmaf(__uint_as_float((V_).y << 16),         (W_), A_[2]);       \
  A_[3] = fmaf(__uint_as_float((V_).y & 0xFFFF0000u), (W_), A_[3]);       \
  A_[4] = fmaf(__uint_as_float((V_).z << 16),         (W_), A_[4]);       \
  A_[5] = fmaf(__uint_as_float((V_).z & 0xFFFF0000u), (W_), A_[5]);       \
  A_[6] = fmaf(__uint_as_float((V_).w << 16),         (W_), A_[6]);       \
  A_[7] = fmaf(__uint_as_float((V_).w & 0xFFFF0000u), (W_), A_[7]);

// ---------------------------------------------------------------------------
// GEMM0 block body (MFMA): h0 = bf16(bf16(x) @ bf16(W0)), 32 rows x 128 cols
// per block, 5 tiles/block.
// ---------------------------------------------------------------------------
__device__ __forceinline__ void gemm0_block(
    int bid, const float* __restrict__ x, const float* __restrict__ W0,
    unsigned short* __restrict__ h0) {
  __shared__ __align__(16) unsigned short xb[32 * 264];
  const int tid  = threadIdx.x;
  const int lane = tid & 63;
  const int wave = tid >> 6;
  const int rb   = wave & 1;
  const int ch   = wave >> 1;
  const int l15  = lane & 15;
  const int g    = lane >> 4;

  bf16x8 Bf[4][8];
#pragma unroll
  for (int cb = 0; cb < 4; ++cb) {
    const int col = ch * 64 + cb * 16 + l15;
#pragma unroll
    for (int q = 0; q < 8; ++q) {
      const int k0 = q * 32 + g * 8;
      uint4 uw;
      {
        __hip_bfloat162 p;
        p.x = __float2bfloat16(W0[(size_t)(k0 + 0) * N_HIDDEN + col]);
        p.y = __float2bfloat16(W0[(size_t)(k0 + 1) * N_HIDDEN + col]);
        uw.x = *(unsigned int*)&p;
        p.x = __float2bfloat16(W0[(size_t)(k0 + 2) * N_HIDDEN + col]);
        p.y = __float2bfloat16(W0[(size_t)(k0 + 3) * N_HIDDEN + col]);
        uw.y = *(unsigned int*)&p;
        p.x = __float2bfloat16(W0[(size_t)(k0 + 4) * N_HIDDEN + col]);
        p.y = __float2bfloat16(W0[(size_t)(k0 + 5) * N_HIDDEN + col]);
        uw.z = *(unsigned int*)&p;
        p.x = __float2bfloat16(W0[(size_t)(k0 + 6) * N_HIDDEN + col]);
        p.y = __float2bfloat16(W0[(size_t)(k0 + 7) * N_HIDDEN + col]);
        uw.w = *(unsigned int*)&p;
      }
      Bf[cb][q] = __builtin_bit_cast(bf16x8, uw);
    }
  }

  for (int t = 0; t < 5; ++t) {
    const int row0 = (bid * 5 + t) * 32;
    __syncthreads();
    for (int i = tid; i < 32 * 128; i += 256) {
      const int row = i >> 7, kp = i & 127;
      const float2 v = *(const float2*)(x + (size_t)(row0 + row) * IN_FEATS + kp * 2);
      __hip_bfloat162 p;
      p.x = __float2bfloat16(v.x);
      p.y = __float2bfloat16(v.y);
      *(unsigned int*)&xb[row * 264 + kp * 2] = *(unsigned int*)&p;
    }
    __syncthreads();

    f32x4 acc[4];
#pragma unroll
    for (int cb = 0; cb < 4; ++cb) acc[cb] = (f32x4){0.f, 0.f, 0.f, 0.f};

#pragma unroll
    for (int q = 0; q < 8; ++q) {
      const bf16x8 a = *(const bf16x8*)&xb[(rb * 16 + l15) * 264 + q * 32 + g * 8];
      acc[0] = __builtin_amdgcn_mfma_f32_16x16x32_bf16(a, Bf[0][q], acc[0], 0, 0, 0);
      acc[1] = __builtin_amdgcn_mfma_f32_16x16x32_bf16(a, Bf[1][q], acc[1], 0, 0, 0);
      acc[2] = __builtin_amdgcn_mfma_f32_16x16x32_bf16(a, Bf[2][q], acc[2], 0, 0, 0);
      acc[3] = __builtin_amdgcn_mfma_f32_16x16x32_bf16(a, Bf[3][q], acc[3], 0, 0, 0);
    }

#pragma unroll
    for (int cb = 0; cb < 4; ++cb) {
      const int col = ch * 64 + cb * 16 + l15;
#pragma unroll
      for (int r = 0; r < 4; ++r) {
        const int row = row0 + rb * 16 + g * 4 + r;
        __hip_bfloat16 hb = __float2bfloat16(acc[cb][r]);
        h0[(size_t)row * N_HIDDEN + col] = *(unsigned short*)&hb;
      }
    }
  }
}

// ---------------------------------------------------------------------------
// 256-thread exclusive scan of histG (block 0 of the combo dispatch).
// ---------------------------------------------------------------------------
__device__ __forceinline__ void gscan256_block(int* __restrict__ histG) {
  __shared__ int partials[256];
  const int t = threadIdx.x;
  const int chunk = (HIST_M + 255) / 256;   // 300
  const int lo = t * chunk;
  const int hi = min(lo + chunk, HIST_M);

  int sum = 0;
  for (int i = lo; i < hi; ++i) sum += histG[i];
  partials[t] = sum;
  __syncthreads();

  for (int off = 1; off < 256; off <<= 1) {
    int v = (t >= off) ? partials[t - off] : 0;
    __syncthreads();
    partials[t] += v;
    __syncthreads();
  }

  int run = (t > 0) ? partials[t - 1] : 0;
  for (int i = lo; i < hi; ++i) {
    const int d = histG[i];
    histG[i] = run;
    run += d;
  }
}

__global__ __launch_bounds__(256) void gscan_gemm0_kernel(
    int* __restrict__ histG, const float* __restrict__ x,
    const float* __restrict__ W0, unsigned short* __restrict__ h0) {
  if (blockIdx.x == 0) gscan256_block(histG);
  else                 gemm0_block(blockIdx.x - 1, x, W0, h0);
}

// ---------------------------------------------------------------------------
// p1hist + (extra block NBLK) W1 -> bf16 B-fragment pre-swizzle.
// w1f[(nt*4+q)*64 + lane] = uint4 of 8 bf16: elems W1[q*32+(lane>>4)*8+i]
//                                            [nt*16+(lane&15)], 0-padded n>=40.
// ---------------------------------------------------------------------------
__global__ __launch_bounds__(256) void p1hist_kernel(
    const int* __restrict__ dst, int* __restrict__ histG,
    const float* __restrict__ W1, uint4* __restrict__ w1f) {
  const int tid = threadIdx.x;
  const int blk = blockIdx.x;

  if (blk == NBLK) {                 // W1 fragment converter
    for (int t = tid; t < 3 * 4 * 64; t += 256) {
      const int ln  = t & 63;
      const int qq  = (t >> 6) & 3;
      const int nt  = t >> 8;
      const int l15 = ln & 15;
      const int g   = ln >> 4;
      const int c   = nt * 16 + l15;
      const int k0  = qq * 32 + g * 8;
      uint4 u;
      __hip_bfloat162 p;
#define W1AT(i_) ((c < OUT_FEATS) ? W1[(size_t)(k0 + (i_)) * OUT_FEATS + c] : 0.f)
      p.x = __float2bfloat16(W1AT(0)); p.y = __float2bfloat16(W1AT(1));
      u.x = *(unsigned int*)&p;
      p.x = __float2bfloat16(W1AT(2)); p.y = __float2bfloat16(W1AT(3));
      u.y = *(unsigned int*)&p;
      p.x = __float2bfloat16(W1AT(4)); p.y = __float2bfloat16(W1AT(5));
      u.z = *(unsigned int*)&p;
      p.x = __float2bfloat16(W1AT(6)); p.y = __float2bfloat16(W1AT(7));
      u.w = *(unsigned int*)&p;
#undef W1AT
      w1f[t] = u;
    }
    return;
  }

  __shared__ int lh[NB];
  for (int i = tid; i < NB; i += 256) lh[i] = 0;
  __syncthreads();

  const int e0 = blk * EPB;
  const int e1 = min(e0 + EPB, N_EDGES);
  for (int i = e0 + tid; i < e1; i += 256)
    atomicAdd(&lh[dst[i] >> 9], 1);
  __syncthreads();

  for (int i = tid; i < NB; i += 256)
    histG[i * NBLK + blk] = lh[i];
}

// ---------------------------------------------------------------------------
// p1scatter v2: LDS-staged. Stage the block's 8192 edges bucket-sorted in
// LDS, then write each bucket run CONTIGUOUSLY to its exact global slot
// (no global atomics, no cross-XCD partial-line write thrash).
// ---------------------------------------------------------------------------
__global__ __launch_bounds__(256) void p1scatter_kernel(
    const int* __restrict__ src, const int* __restrict__ dst,
    const float* __restrict__ ew, const int* __restrict__ histG,
    uint2* __restrict__ bucketed) {
  __shared__ uint2 stage[EPB];          // 64 KB
  __shared__ unsigned char sbkt[EPB];   // 8 KB
  __shared__ int lcnt[NB];
  __shared__ int lbase[NB];
  __shared__ int spart[256];
  const int tid = threadIdx.x;
  const int blk = blockIdx.x;
  const int e0 = blk * EPB;
  const int e1 = min(e0 + EPB, N_EDGES);

  for (int i = tid; i < NB; i += 256) lcnt[i] = 0;
  __syncthreads();

  // pass A: count
  for (int i = e0 + tid; i < e1; i += 256)
    atomicAdd(&lcnt[dst[i] >> 9], 1);
  __syncthreads();

  // local exclusive scan of the 196 counts
  const int myv = (tid < NB) ? lcnt[tid] : 0;
  spart[tid] = myv;
  __syncthreads();
  for (int off = 1; off < 256; off <<= 1) {
    int u = (tid >= off) ? spart[tid - off] : 0;
    __syncthreads();
    spart[tid] += u;
    __syncthreads();
  }
  if (tid < NB) { lbase[tid] = spart[tid] - myv; lcnt[tid] = spart[tid] - myv; }
  __syncthreads();

  // pass B: stage into LDS, bucket-sorted
  for (int i = e0 + tid; i < e1; i += 256) {
    const int d = dst[i];
    const int b = d >> 9;
    const int pos = atomicAdd(&lcnt[b], 1);
    stage[pos] = make_uint2((unsigned)src[i] | ((unsigned)(d & 511) << 17),
                            __float_as_uint(ew[i]));
    sbkt[pos] = (unsigned char)b;
  }
  __syncthreads();

  // pass C: contiguous, coalesced write-out to exact global positions
  const int n = e1 - e0;
  for (int i = tid; i < n; i += 256) {
    const int b = sbkt[i];
    const int gpos = histG[b * NBLK + blk] + (i - lbase[b]);
    bucketed[gpos] = stage[i];
  }
}

__global__ __launch_bounds__(256) void p2place_kernel(
    const uint2* __restrict__ bucketed, const int* __restrict__ histG,
    int* __restrict__ offsets, int2* __restrict__ srcw) {
  __shared__ int cnt[512];
  __shared__ int part[256];
  const int t = threadIdx.x;
  const int b = blockIdx.x;
  const int node0 = b << 9;
  const int beg = histG[b * NBLK];
  const int end = (b == NB - 1) ? N_EDGES : histG[(b + 1) * NBLK];

  cnt[t] = 0; cnt[t + 256] = 0;
  __syncthreads();

  for (int j = beg + t; j < end; j += 256)
    atomicAdd(&cnt[bucketed[j].x >> 17], 1);
  __syncthreads();

  const int a0 = cnt[2 * t];
  const int a1 = cnt[2 * t + 1];
  part[t] = a0 + a1;
  __syncthreads();
  for (int off = 1; off < 256; off <<= 1) {
    int v = (t >= off) ? part[t - off] : 0;
    __syncthreads();
    part[t] += v;
    __syncthreads();
  }
  const int base = (t > 0) ? part[t - 1] : 0;

  const int o0 = beg + base;
  const int o1 = o0 + a0;
  cnt[2 * t]     = o0;
  cnt[2 * t + 1] = o1;
  const int n0 = node0 + 2 * t;
  if (n0 < N_NODES)     offsets[n0]     = o0;
  if (n0 + 1 < N_NODES) offsets[n0 + 1] = o1;
  if (b == NB - 1 && t == 0) offsets[N_NODES] = N_EDGES;
  __syncthreads();

  for (int j = beg + t; j < end; j += 256) {
    const uint2 en = bucketed[j];
    const int slot = atomicAdd(&cnt[en.x >> 17], 1);
    srcw[slot] = make_int2((int)(en.x & 0x1FFFFu), (int)en.y);
  }
}

// ---------------------------------------------------------------------------
// Fused gather0 + bias + ReLU + MFMA GEMM1 epilogue.
// Gather: 16 lanes/edge, dwordx4, 2 groups in flight. Epilogue: the per-node
// 128x40 matvec is now 12 MFMAs across 3 waves (A = 4 node rows of hs,
// B = pre-swizzled w1f fragments) instead of 128 scalar FMAs x 40 lanes.
// h1 is written split: h1a = feats 0-31 (64 B/row), h1c = feats 32-39
// (16 B/row; 1.6 MB table -> L2-resident for gather1).
// ---------------------------------------------------------------------------
__global__ __launch_bounds__(256) void gather0_gemm1_kernel(
    const uint4* __restrict__ h0q, const int2* __restrict__ srcw,
    const int* __restrict__ offsets, const float* __restrict__ b0,
    const uint4* __restrict__ w1f, unsigned short* __restrict__ h1a,
    unsigned short* __restrict__ h1c) {
  __shared__ float hs[4][N_HIDDEN];
  const int wave = threadIdx.x >> 6;
  const int lane = threadIdx.x & 63;
  const int node = blockIdx.x * 4 + wave;
  const int q    = lane >> 4;       // edge slot 0..3 within a 4-edge group
  const int fl   = lane & 15;       // feature chunk: feats [fl*8, fl*8+8)

  const int beg = __builtin_amdgcn_readfirstlane(offsets[node]);
  const int end = __builtin_amdgcn_readfirstlane(offsets[node + 1]);

  float acc[8] = {0.f, 0.f, 0.f, 0.f, 0.f, 0.f, 0.f, 0.f};

  if (end > beg) {
    const int e1 = end - 1;
    int2 sA = srcw[min(beg + q, e1)];
    int2 sB = srcw[min(beg + 4 + q, e1)];
    for (int j = beg; j < end; j += 8) {
      const float wA = (j + q < end)     ? __int_as_float(sA.y) : 0.f;
      const float wB = (j + 4 + q < end) ? __int_as_float(sB.y) : 0.f;
      const uint4 vA = h0q[(size_t)(unsigned)sA.x * 16 + fl];
      const uint4 vB = h0q[(size_t)(unsigned)sB.x * 16 + fl];
      const int jn = j + 8;
      if (jn < end) {                 // prefetch next groups' meta
        sA = srcw[min(jn + q, e1)];
        sB = srcw[min(jn + 4 + q, e1)];
      }
      ACC8(acc, vA, wA)
      ACC8(acc, vB, wB)
    }
  }

  // reduce the 4 edge-groups (lanes xor 16, 32 hold same features)
#pragma unroll
  for (int i = 0; i < 8; ++i) {
    acc[i] += __shfl_xor(acc[i], 16);
    acc[i] += __shfl_xor(acc[i], 32);
  }

  // bias + ReLU, one quarter-wave writes the 128-float row to LDS
  if (q == 0) {
    const int f0 = fl * 8;
    float t[8];
#pragma unroll
    for (int i = 0; i < 8; ++i) {
      const float v = acc[i] + b0[f0 + i];
      t[i] = v > 0.f ? v : 0.f;
    }
    *(float4*)&hs[wave][f0]     = make_float4(t[0], t[1], t[2], t[3]);
    *(float4*)&hs[wave][f0 + 4] = make_float4(t[4], t[5], t[6], t[7]);
  }
  __syncthreads();

  // --- MFMA epilogue: h1 = hs(4x128) @ W1(128x40), waves 0-2 = N-tiles ---
  if (wave < 3) {
    const int l15 = lane & 15;
    const int g   = lane >> 4;
    f32x4 c = {0.f, 0.f, 0.f, 0.f};
#pragma unroll
    for (int qq = 0; qq < 4; ++qq) {
      uint4 ua = make_uint4(0, 0, 0, 0);
      if (l15 < 4) {                          // A rows 0-3 = this block's nodes
        const float* hrow = &hs[l15][qq * 32 + g * 8];
        __hip_bfloat162 p;
        p.x = __float2bfloat16(hrow[0]); p.y = __float2bfloat16(hrow[1]);
        ua.x = *(unsigned int*)&p;
        p.x = __float2bfloat16(hrow[2]); p.y = __float2bfloat16(hrow[3]);
        ua.y = *(unsigned int*)&p;
        p.x = __float2bfloat16(hrow[4]); p.y = __float2bfloat16(hrow[5]);
        ua.z = *(unsigned int*)&p;
        p.x = __float2bfloat16(hrow[6]); p.y = __float2bfloat16(hrow[7]);
        ua.w = *(unsigned int*)&p;
      }
      const uint4 ub = w1f[(wave * 4 + qq) * 64 + lane];
      c = __builtin_amdgcn_mfma_f32_16x16x32_bf16(
            __builtin_bit_cast(bf16x8, ua), __builtin_bit_cast(bf16x8, ub),
            c, 0, 0, 0);
    }
    // C: col = lane&15 (feat within tile), row = (lane>>4)*4 + r (node)
    if (g == 0) {
#pragma unroll
      for (int r = 0; r < 4; ++r) {
        const int nodeR = blockIdx.x * 4 + r;
        const int f = wave * 16 + l15;
        __hip_bfloat16 hb = __float2bfloat16(c[r]);
        const unsigned short v16 = *(unsigned short*)&hb;
        if (f < 32)              h1a[(size_t)nodeR * 32 + f] = v16;
        else if (f < OUT_FEATS)  h1c[(size_t)nodeR * 8 + (f - 32)] = v16;
      }
    }
  }
}

// ---------------------------------------------------------------------------
// Fused gather1 + bias + log_softmax, on split h1 (64 B + 16 B rows).
// 4 lanes/edge on h1a (1 line/edge), h1c gathered by fl==0 lanes from the
// L2-resident 1.6 MB table. 2 groups of 16 edges in flight.
// ---------------------------------------------------------------------------
__global__ __launch_bounds__(256) void gather1_lsm_kernel(
    const uint4* __restrict__ h1aq, const uint4* __restrict__ h1cq,
    const int2* __restrict__ srcw, const int* __restrict__ offsets,
    const float* __restrict__ b1, float* __restrict__ out) {
  const int wave = threadIdx.x >> 6;
  const int lane = threadIdx.x & 63;
  const int node = blockIdx.x * 4 + wave;
  const int g  = lane >> 2;         // edge slot 0..15 within a 16-edge group
  const int fl = lane & 3;          // feats [fl*8, fl*8+8) of h1a

  const int beg = __builtin_amdgcn_readfirstlane(offsets[node]);
  const int end = __builtin_amdgcn_readfirstlane(offsets[node + 1]);

  float acc[8]  = {0.f, 0.f, 0.f, 0.f, 0.f, 0.f, 0.f, 0.f};
  float acc2[8] = {0.f, 0.f, 0.f, 0.f, 0.f, 0.f, 0.f, 0.f};

  if (end > beg) {
    const int e1 = end - 1;
    int2 sA = srcw[min(beg + g, e1)];
    int2 sB = srcw[min(beg + 16 + g, e1)];
    for (int j = beg; j < end; j += 32) {
      const float wA = (j + g < end)      ? __int_as_float(sA.y) : 0.f;
      const float wB = (j + 16 + g < end) ? __int_as_float(sB.y) : 0.f;
      const uint4 vA = h1aq[(size_t)(unsigned)sA.x * 4 + fl];
      const uint4 vB = h1aq[(size_t)(unsigned)sB.x * 4 + fl];
      uint4 cA = make_uint4(0, 0, 0, 0), cB = make_uint4(0, 0, 0, 0);
      if (fl == 0) {
        cA = h1cq[(unsigned)sA.x];
        cB = h1cq[(unsigned)sB.x];
      }
      const int jn = j + 32;
      if (jn < end) {
        sA = srcw[min(jn + g, e1)];
        sB = srcw[min(jn + 16 + g, e1)];
      }
      ACC8(acc, vA, wA)
      ACC8(acc, vB, wB)
      if (fl == 0) {
        ACC8(acc2, cA, wA)
        ACC8(acc2, cB, wB)
      }
    }
  }

  // reduce across the 16 edge-groups (xor 4,8,16,32), then broadcast acc2
  // across fl (fl!=0 lanes hold 0, so xor 1,2 completes the sum everywhere)
#pragma unroll
  for (int i = 0; i < 8; ++i) {
    acc[i]  += __shfl_xor(acc[i], 4);
    acc[i]  += __shfl_xor(acc[i], 8);
    acc[i]  += __shfl_xor(acc[i], 16);
    acc[i]  += __shfl_xor(acc[i], 32);
    acc2[i] += __shfl_xor(acc2[i], 4);
    acc2[i] += __shfl_xor(acc2[i], 8);
    acc2[i] += __shfl_xor(acc2[i], 16);
    acc2[i] += __shfl_xor(acc2[i], 32);
    acc2[i] += __shfl_xor(acc2[i], 1);
    acc2[i] += __shfl_xor(acc2[i], 2);
  }

  // biases
  const int f0 = fl * 8;
  float m = -INFINITY;
#pragma unroll
  for (int i = 0; i < 8; ++i) {
    acc[i]  += b1[f0 + i];
    acc2[i] += b1[32 + i];
    m = fmaxf(m, acc[i]);
    m = fmaxf(m, acc2[i]);
  }
  m = fmaxf(m, __shfl_xor(m, 1));
  m = fmaxf(m, __shfl_xor(m, 2));

  float s = 0.f;
#pragma unroll
  for (int i = 0; i < 8; ++i) s += expf(acc[i] - m);
  s += __shfl_xor(s, 1);
  s += __shfl_xor(s, 2);
  float s2 = 0.f;
#pragma unroll
  for (int i = 0; i < 8; ++i) s2 += expf(acc2[i] - m);
  s += s2;

  const float lse = m + logf(s);
  if (lane < 4) {                   // g==0: feats fl*8..fl*8+8
    float* op = out + (size_t)node * OUT_FEATS + fl * 8;
    *(float4*)op       = make_float4(acc[0] - lse, acc[1] - lse,
                                     acc[2] - lse, acc[3] - lse);
    *(float4*)(op + 4) = make_float4(acc[4] - lse, acc[5] - lse,
                                     acc[6] - lse, acc[7] - lse);
  } else if (lane == 4) {           // feats 32-39
    float* op = out + (size_t)node * OUT_FEATS + 32;
    *(float4*)op       = make_float4(acc2[0] - lse, acc2[1] - lse,
                                     acc2[2] - lse, acc2[3] - lse);
    *(float4*)(op + 4) = make_float4(acc2[4] - lse, acc2[5] - lse,
                                     acc2[6] - lse, acc2[7] - lse);
  }
}

// ---------------------------------------------------------------------------
extern "C" void kernel_launch(void* const* d_in, const int* in_sizes, int n_in,
                              void* d_out, int out_size, void* d_ws, size_t ws_size,
                              hipStream_t stream) {
  const float* x   = (const float*)d_in[0];
  const float* W0  = (const float*)d_in[1];
  const float* b0  = (const float*)d_in[2];
  const float* W1  = (const float*)d_in[3];
  const float* b1  = (const float*)d_in[4];
  const float* ew  = (const float*)d_in[5];
  const int*   src = (const int*)d_in[6];
  const int*   dst = (const int*)d_in[7];
  float* out = (float*)d_out;

  // Workspace layout, peak ~85.6 MB (ws >= 102.4 MB):
  //   h0b2     [0,          25,600,000)   N*128 bf16
  //   srcw     [25,600,000, 51,200,000)   E int2, dst-sorted
  //   bucketed [51,200,000, 76,800,000)   E uint2, bucket-partitioned
  //   offsets  [76,800,000, 77,200,064)   N+1 int
  //   histG    [77,200,064, 77,506,624)   NB*NBLK int
  //   h1a      [77,506,624, 83,906,624)   N*32 bf16 (64 B rows, feats 0-31)
  //   h1c      [83,906,624, 85,506,624)   N*8  bf16 (16 B rows, feats 32-39)
  //   w1f      [85,506,624, 85,518,912)   768 uint4 (pre-swizzled W1 B-frags)
  char* ws = (char*)d_ws;
  unsigned int* h0b2 = (unsigned int*)(ws);
  int2*  srcw     = (int2*)(ws + 25600000);
  uint2* bucketed = (uint2*)(ws + 51200000);
  int*   offsets  = (int*)(ws + 76800000);
  int*   histG    = (int*)(ws + 77200064);
  unsigned short* h1a = (unsigned short*)(ws + 77506624);
  unsigned short* h1c = (unsigned short*)(ws + 83906624);
  uint4* w1f      = (uint4*)(ws + 85506624);

  p1hist_kernel<<<NBLK + 1, 256, 0, stream>>>(dst, histG, W1, w1f);
  // gscan (block 0) hidden under gemm0 (blocks 1..625) in one dispatch.
  gscan_gemm0_kernel<<<626, 256, 0, stream>>>(histG, x, W0, (unsigned short*)h0b2);
  p1scatter_kernel<<<NBLK, 256, 0, stream>>>(src, dst, ew, histG, bucketed);
  p2place_kernel<<<NB, 256, 0, stream>>>(bucketed, histG, offsets, srcw);

  gather0_gemm1_kernel<<<N_NODES / 4, 256, 0, stream>>>(
      (const uint4*)h0b2, srcw, offsets, b0, (const uint4*)w1f, h1a, h1c);
  gather1_lsm_kernel<<<N_NODES / 4, 256, 0, stream>>>(
      (const uint4*)h1a, (const uint4*)h1c, srcw, offsets, b1, out);
}

// Round 4
// 511.165 us; speedup vs baseline: 1.3245x; 1.2118x over previous
//
#include <hip/hip_runtime.h>
#include <hip/hip_bf16.h>
#include <cstdint>
#include <cstddef>

#define N_NODES   100000
#define N_EDGES   3200000
#define IN_FEATS  256
#define N_HIDDEN  128
#define OUT_FEATS 40

// Bucket partition: bucket = dst >> 9 (512 nodes/bucket)
#define NB        196
#define EPB       8192
#define NBLK      391
#define HIST_M    (NB * NBLK)
#define N_TILES   3125            // 100000 / 32
#define TPB       2               // gemm0 tiles per block
#define G0BLKS    ((N_TILES + TPB - 1) / TPB)   // 1563

typedef __attribute__((ext_vector_type(8))) __bf16 bf16x8;
typedef __attribute__((ext_vector_type(4))) float f32x4;

// unpack a uint4 holding 8 bf16 (low short = even feature) and fma all 8
// into array A_. Params named V_/W_ to avoid .x/.y/.z/.w collision.
#define ACC8(A_, V_, W_)                                                  \
  A_[0] = fmaf(__uint_as_float((V_).x << 16),         (W_), A_[0]);       \
  A_[1] = fmaf(__uint_as_float((V_).x & 0xFFFF0000u), (W_), A_[1]);       \
  A_[2] = fmaf(__uint_as_float((V_).y << 16),         (W_), A_[2]);       \
  A_[3] = fmaf(__uint_as_float((V_).y & 0xFFFF0000u), (W_), A_[3]);       \
  A_[4] = fmaf(__uint_as_float((V_).z << 16),         (W_), A_[4]);       \
  A_[5] = fmaf(__uint_as_float((V_).z & 0xFFFF0000u), (W_), A_[5]);       \
  A_[6] = fmaf(__uint_as_float((V_).w << 16),         (W_), A_[6]);       \
  A_[7] = fmaf(__uint_as_float((V_).w & 0xFFFF0000u), (W_), A_[7]);

// ---------------------------------------------------------------------------
// GEMM0 block body (MFMA): h0 = bf16(bf16(x) @ bf16(W0)), 32 rows x 128 cols
// per tile, TPB tiles/block. W0 comes pre-swizzled as bf16 B-fragments (w0f),
// so the prologue is 32 coalesced L2-hit dwordx4 loads (was 256 scalar f32
// loads, rematerialized per tile by the compiler at VGPR=112).
// ---------------------------------------------------------------------------
__device__ __forceinline__ void gemm0_block(
    int bid, const float* __restrict__ x, const uint4* __restrict__ w0f,
    unsigned short* __restrict__ h0) {
  __shared__ __align__(16) unsigned short xb[32 * 264];
  const int tid  = threadIdx.x;
  const int lane = tid & 63;
  const int wave = tid >> 6;
  const int rb   = wave & 1;
  const int ch   = wave >> 1;
  const int l15  = lane & 15;
  const int g    = lane >> 4;

  bf16x8 Bf[4][8];
#pragma unroll
  for (int cb = 0; cb < 4; ++cb)
#pragma unroll
    for (int q = 0; q < 8; ++q)
      Bf[cb][q] = __builtin_bit_cast(bf16x8, w0f[((ch * 4 + cb) * 8 + q) * 64 + lane]);

  for (int t = 0; t < TPB; ++t) {
    const int tile = bid * TPB + t;
    if (tile >= N_TILES) break;
    const int row0 = tile * 32;
    __syncthreads();
    for (int i = tid; i < 32 * 128; i += 256) {
      const int row = i >> 7, kp = i & 127;
      const float2 v = *(const float2*)(x + (size_t)(row0 + row) * IN_FEATS + kp * 2);
      __hip_bfloat162 p;
      p.x = __float2bfloat16(v.x);
      p.y = __float2bfloat16(v.y);
      *(unsigned int*)&xb[row * 264 + kp * 2] = *(unsigned int*)&p;
    }
    __syncthreads();

    f32x4 acc[4];
#pragma unroll
    for (int cb = 0; cb < 4; ++cb) acc[cb] = (f32x4){0.f, 0.f, 0.f, 0.f};

#pragma unroll
    for (int q = 0; q < 8; ++q) {
      const bf16x8 a = *(const bf16x8*)&xb[(rb * 16 + l15) * 264 + q * 32 + g * 8];
      acc[0] = __builtin_amdgcn_mfma_f32_16x16x32_bf16(a, Bf[0][q], acc[0], 0, 0, 0);
      acc[1] = __builtin_amdgcn_mfma_f32_16x16x32_bf16(a, Bf[1][q], acc[1], 0, 0, 0);
      acc[2] = __builtin_amdgcn_mfma_f32_16x16x32_bf16(a, Bf[2][q], acc[2], 0, 0, 0);
      acc[3] = __builtin_amdgcn_mfma_f32_16x16x32_bf16(a, Bf[3][q], acc[3], 0, 0, 0);
    }

#pragma unroll
    for (int cb = 0; cb < 4; ++cb) {
      const int col = ch * 64 + cb * 16 + l15;
#pragma unroll
      for (int r = 0; r < 4; ++r) {
        const int row = row0 + rb * 16 + g * 4 + r;
        __hip_bfloat16 hb = __float2bfloat16(acc[cb][r]);
        h0[(size_t)row * N_HIDDEN + col] = *(unsigned short*)&hb;
      }
    }
  }
}

// ---------------------------------------------------------------------------
// Parallel 2-level scan: block b computes bucket b's base by reducing
// bsum[0..b-1] (784 B, L2-hit), then pair-scans its own 391 contiguous
// entries (coalesced). Replaces the 175 us single-block serial scan.
// ---------------------------------------------------------------------------
__device__ __forceinline__ void bucket_scan_block(
    int b, const int* __restrict__ bsum, int* __restrict__ histG) {
  __shared__ int sh[256];
  __shared__ int pr[256];
  const int t = threadIdx.x;

  sh[t] = (t < b) ? bsum[t] : 0;          // b <= 195 < 256
  __syncthreads();
#pragma unroll
  for (int off = 128; off > 0; off >>= 1) {
    if (t < off) sh[t] += sh[t + off];
    __syncthreads();
  }
  const int base = sh[0];

  const int row = b * NBLK;
  const int i0 = 2 * t, i1 = 2 * t + 1;
  int a = 0, c = 0;
  if (t < 196) {
    a = histG[row + i0];                  // i0 <= 390
    if (i1 < NBLK) c = histG[row + i1];
  }
  pr[t] = a + c;
  __syncthreads();
  for (int off = 1; off < 256; off <<= 1) {
    int v = (t >= off) ? pr[t - off] : 0;
    __syncthreads();
    pr[t] += v;
    __syncthreads();
  }
  if (t < 196) {
    const int ebase = (t > 0) ? pr[t - 1] : 0;
    histG[row + i0] = base + ebase;
    if (i1 < NBLK) histG[row + i1] = base + ebase + a;
  }
}

// Combo: blocks 0..195 = parallel bucket scans, blocks 196.. = gemm0.
__global__ __launch_bounds__(256) void bscan_gemm0_kernel(
    const int* __restrict__ bsum, int* __restrict__ histG,
    const float* __restrict__ x, const uint4* __restrict__ w0f,
    unsigned short* __restrict__ h0) {
  if (blockIdx.x < NB) bucket_scan_block(blockIdx.x, bsum, histG);
  else                 gemm0_block(blockIdx.x - NB, x, w0f, h0);
}

// ---------------------------------------------------------------------------
// p1hist: blocks 0..NBLK-1 = histogram (+ bsum accumulate);
// block NBLK = W1 fragment pre-swizzle; blocks NBLK+1..NBLK+8 = W0 pre-swizzle.
// w1f[(nt*4+q)*64+lane], w0f[(ct*8+q)*64+lane]: uint4 of 8 bf16, B-fragment
// layout for mfma_f32_16x16x32_bf16 (elems W[q*32+(lane>>4)*8+i][tile*16+(lane&15)]).
// ---------------------------------------------------------------------------
__global__ __launch_bounds__(256) void p1hist_kernel(
    const int* __restrict__ dst, int* __restrict__ histG,
    const float* __restrict__ W1, uint4* __restrict__ w1f,
    const float* __restrict__ W0, uint4* __restrict__ w0f,
    int* __restrict__ bsum) {
  const int tid = threadIdx.x;
  const int blk = blockIdx.x;

  if (blk >= NBLK) {
    if (blk == NBLK) {                    // W1 fragment converter (40 cols, pad)
      for (int t = tid; t < 3 * 4 * 64; t += 256) {
        const int ln  = t & 63;
        const int qq  = (t >> 6) & 3;
        const int nt  = t >> 8;
        const int l15 = ln & 15;
        const int gg  = ln >> 4;
        const int c   = nt * 16 + l15;
        const int k0  = qq * 32 + gg * 8;
        uint4 u;
        __hip_bfloat162 p;
#define W1AT(i_) ((c < OUT_FEATS) ? W1[(size_t)(k0 + (i_)) * OUT_FEATS + c] : 0.f)
        p.x = __float2bfloat16(W1AT(0)); p.y = __float2bfloat16(W1AT(1));
        u.x = *(unsigned int*)&p;
        p.x = __float2bfloat16(W1AT(2)); p.y = __float2bfloat16(W1AT(3));
        u.y = *(unsigned int*)&p;
        p.x = __float2bfloat16(W1AT(4)); p.y = __float2bfloat16(W1AT(5));
        u.z = *(unsigned int*)&p;
        p.x = __float2bfloat16(W1AT(6)); p.y = __float2bfloat16(W1AT(7));
        u.w = *(unsigned int*)&p;
#undef W1AT
        w1f[t] = u;
      }
    } else {                              // W0 fragment converter (128 cols)
      const int pb = blk - NBLK - 1;      // 0..7
      for (int fi = pb * 512 + tid; fi < pb * 512 + 512; fi += 256) {
        const int ln  = fi & 63;
        const int qq  = (fi >> 6) & 7;
        const int ct  = fi >> 9;
        const int col = ct * 16 + (ln & 15);
        const int k0  = qq * 32 + (ln >> 4) * 8;
        uint4 u;
        __hip_bfloat162 p;
        p.x = __float2bfloat16(W0[(size_t)(k0 + 0) * N_HIDDEN + col]);
        p.y = __float2bfloat16(W0[(size_t)(k0 + 1) * N_HIDDEN + col]);
        u.x = *(unsigned int*)&p;
        p.x = __float2bfloat16(W0[(size_t)(k0 + 2) * N_HIDDEN + col]);
        p.y = __float2bfloat16(W0[(size_t)(k0 + 3) * N_HIDDEN + col]);
        u.y = *(unsigned int*)&p;
        p.x = __float2bfloat16(W0[(size_t)(k0 + 4) * N_HIDDEN + col]);
        p.y = __float2bfloat16(W0[(size_t)(k0 + 5) * N_HIDDEN + col]);
        u.z = *(unsigned int*)&p;
        p.x = __float2bfloat16(W0[(size_t)(k0 + 6) * N_HIDDEN + col]);
        p.y = __float2bfloat16(W0[(size_t)(k0 + 7) * N_HIDDEN + col]);
        u.w = *(unsigned int*)&p;
        w0f[fi] = u;
      }
    }
    return;
  }

  __shared__ int lh[NB];
  for (int i = tid; i < NB; i += 256) lh[i] = 0;
  __syncthreads();

  const int e0 = blk * EPB;
  const int e1 = min(e0 + EPB, N_EDGES);
  for (int i = e0 + tid; i < e1; i += 256)
    atomicAdd(&lh[dst[i] >> 9], 1);
  __syncthreads();

  for (int i = tid; i < NB; i += 256) {
    histG[i * NBLK + blk] = lh[i];
    atomicAdd(&bsum[i], lh[i]);
  }
}

// ---------------------------------------------------------------------------
// p1scatter: LDS-staged, bucket-contiguous global writes.
// ---------------------------------------------------------------------------
__global__ __launch_bounds__(256) void p1scatter_kernel(
    const int* __restrict__ src, const int* __restrict__ dst,
    const float* __restrict__ ew, const int* __restrict__ histG,
    uint2* __restrict__ bucketed) {
  __shared__ uint2 stage[EPB];          // 64 KB
  __shared__ unsigned char sbkt[EPB];   // 8 KB
  __shared__ int lcnt[NB];
  __shared__ int lbase[NB];
  __shared__ int spart[256];
  const int tid = threadIdx.x;
  const int blk = blockIdx.x;
  const int e0 = blk * EPB;
  const int e1 = min(e0 + EPB, N_EDGES);

  for (int i = tid; i < NB; i += 256) lcnt[i] = 0;
  __syncthreads();

  for (int i = e0 + tid; i < e1; i += 256)
    atomicAdd(&lcnt[dst[i] >> 9], 1);
  __syncthreads();

  const int myv = (tid < NB) ? lcnt[tid] : 0;
  spart[tid] = myv;
  __syncthreads();
  for (int off = 1; off < 256; off <<= 1) {
    int u = (tid >= off) ? spart[tid - off] : 0;
    __syncthreads();
    spart[tid] += u;
    __syncthreads();
  }
  if (tid < NB) { lbase[tid] = spart[tid] - myv; lcnt[tid] = spart[tid] - myv; }
  __syncthreads();

  for (int i = e0 + tid; i < e1; i += 256) {
    const int d = dst[i];
    const int b = d >> 9;
    const int pos = atomicAdd(&lcnt[b], 1);
    stage[pos] = make_uint2((unsigned)src[i] | ((unsigned)(d & 511) << 17),
                            __float_as_uint(ew[i]));
    sbkt[pos] = (unsigned char)b;
  }
  __syncthreads();

  const int n = e1 - e0;
  for (int i = tid; i < n; i += 256) {
    const int b = sbkt[i];
    const int gpos = histG[b * NBLK + blk] + (i - lbase[b]);
    bucketed[gpos] = stage[i];
  }
}

__global__ __launch_bounds__(256) void p2place_kernel(
    const uint2* __restrict__ bucketed, const int* __restrict__ histG,
    int* __restrict__ offsets, int2* __restrict__ srcw) {
  __shared__ int cnt[512];
  __shared__ int part[256];
  const int t = threadIdx.x;
  const int b = blockIdx.x;
  const int node0 = b << 9;
  const int beg = histG[b * NBLK];
  const int end = (b == NB - 1) ? N_EDGES : histG[(b + 1) * NBLK];

  cnt[t] = 0; cnt[t + 256] = 0;
  __syncthreads();

  for (int j = beg + t; j < end; j += 256)
    atomicAdd(&cnt[bucketed[j].x >> 17], 1);
  __syncthreads();

  const int a0 = cnt[2 * t];
  const int a1 = cnt[2 * t + 1];
  part[t] = a0 + a1;
  __syncthreads();
  for (int off = 1; off < 256; off <<= 1) {
    int v = (t >= off) ? part[t - off] : 0;
    __syncthreads();
    part[t] += v;
    __syncthreads();
  }
  const int base = (t > 0) ? part[t - 1] : 0;

  const int o0 = beg + base;
  const int o1 = o0 + a0;
  cnt[2 * t]     = o0;
  cnt[2 * t + 1] = o1;
  const int n0 = node0 + 2 * t;
  if (n0 < N_NODES)     offsets[n0]     = o0;
  if (n0 + 1 < N_NODES) offsets[n0 + 1] = o1;
  if (b == NB - 1 && t == 0) offsets[N_NODES] = N_EDGES;
  __syncthreads();

  for (int j = beg + t; j < end; j += 256) {
    const uint2 en = bucketed[j];
    const int slot = atomicAdd(&cnt[en.x >> 17], 1);
    srcw[slot] = make_int2((int)(en.x & 0x1FFFFu), (int)en.y);
  }
}

// ---------------------------------------------------------------------------
// Fused gather0 + bias + ReLU + MFMA GEMM1 epilogue (unchanged from R3).
// ---------------------------------------------------------------------------
__global__ __launch_bounds__(256) void gather0_gemm1_kernel(
    const uint4* __restrict__ h0q, const int2* __restrict__ srcw,
    const int* __restrict__ offsets, const float* __restrict__ b0,
    const uint4* __restrict__ w1f, unsigned short* __restrict__ h1a,
    unsigned short* __restrict__ h1c) {
  __shared__ float hs[4][N_HIDDEN];
  const int wave = threadIdx.x >> 6;
  const int lane = threadIdx.x & 63;
  const int node = blockIdx.x * 4 + wave;
  const int q    = lane >> 4;
  const int fl   = lane & 15;

  const int beg = __builtin_amdgcn_readfirstlane(offsets[node]);
  const int end = __builtin_amdgcn_readfirstlane(offsets[node + 1]);

  float acc[8] = {0.f, 0.f, 0.f, 0.f, 0.f, 0.f, 0.f, 0.f};

  if (end > beg) {
    const int e1 = end - 1;
    int2 sA = srcw[min(beg + q, e1)];
    int2 sB = srcw[min(beg + 4 + q, e1)];
    for (int j = beg; j < end; j += 8) {
      const float wA = (j + q < end)     ? __int_as_float(sA.y) : 0.f;
      const float wB = (j + 4 + q < end) ? __int_as_float(sB.y) : 0.f;
      const uint4 vA = h0q[(size_t)(unsigned)sA.x * 16 + fl];
      const uint4 vB = h0q[(size_t)(unsigned)sB.x * 16 + fl];
      const int jn = j + 8;
      if (jn < end) {
        sA = srcw[min(jn + q, e1)];
        sB = srcw[min(jn + 4 + q, e1)];
      }
      ACC8(acc, vA, wA)
      ACC8(acc, vB, wB)
    }
  }

#pragma unroll
  for (int i = 0; i < 8; ++i) {
    acc[i] += __shfl_xor(acc[i], 16);
    acc[i] += __shfl_xor(acc[i], 32);
  }

  if (q == 0) {
    const int f0 = fl * 8;
    float t[8];
#pragma unroll
    for (int i = 0; i < 8; ++i) {
      const float v = acc[i] + b0[f0 + i];
      t[i] = v > 0.f ? v : 0.f;
    }
    *(float4*)&hs[wave][f0]     = make_float4(t[0], t[1], t[2], t[3]);
    *(float4*)&hs[wave][f0 + 4] = make_float4(t[4], t[5], t[6], t[7]);
  }
  __syncthreads();

  if (wave < 3) {
    const int l15 = lane & 15;
    const int g   = lane >> 4;
    f32x4 c = {0.f, 0.f, 0.f, 0.f};
#pragma unroll
    for (int qq = 0; qq < 4; ++qq) {
      uint4 ua = make_uint4(0, 0, 0, 0);
      if (l15 < 4) {
        const float* hrow = &hs[l15][qq * 32 + g * 8];
        __hip_bfloat162 p;
        p.x = __float2bfloat16(hrow[0]); p.y = __float2bfloat16(hrow[1]);
        ua.x = *(unsigned int*)&p;
        p.x = __float2bfloat16(hrow[2]); p.y = __float2bfloat16(hrow[3]);
        ua.y = *(unsigned int*)&p;
        p.x = __float2bfloat16(hrow[4]); p.y = __float2bfloat16(hrow[5]);
        ua.z = *(unsigned int*)&p;
        p.x = __float2bfloat16(hrow[6]); p.y = __float2bfloat16(hrow[7]);
        ua.w = *(unsigned int*)&p;
      }
      const uint4 ub = w1f[(wave * 4 + qq) * 64 + lane];
      c = __builtin_amdgcn_mfma_f32_16x16x32_bf16(
            __builtin_bit_cast(bf16x8, ua), __builtin_bit_cast(bf16x8, ub),
            c, 0, 0, 0);
    }
    if (g == 0) {
#pragma unroll
      for (int r = 0; r < 4; ++r) {
        const int nodeR = blockIdx.x * 4 + r;
        const int f = wave * 16 + l15;
        __hip_bfloat16 hb = __float2bfloat16(c[r]);
        const unsigned short v16 = *(unsigned short*)&hb;
        if (f < 32)              h1a[(size_t)nodeR * 32 + f] = v16;
        else if (f < OUT_FEATS)  h1c[(size_t)nodeR * 8 + (f - 32)] = v16;
      }
    }
  }
}

// ---------------------------------------------------------------------------
// Fused gather1 + bias + log_softmax (unchanged from R3).
// ---------------------------------------------------------------------------
__global__ __launch_bounds__(256) void gather1_lsm_kernel(
    const uint4* __restrict__ h1aq, const uint4* __restrict__ h1cq,
    const int2* __restrict__ srcw, const int* __restrict__ offsets,
    const float* __restrict__ b1, float* __restrict__ out) {
  const int wave = threadIdx.x >> 6;
  const int lane = threadIdx.x & 63;
  const int node = blockIdx.x * 4 + wave;
  const int g  = lane >> 2;
  const int fl = lane & 3;

  const int beg = __builtin_amdgcn_readfirstlane(offsets[node]);
  const int end = __builtin_amdgcn_readfirstlane(offsets[node + 1]);

  float acc[8]  = {0.f, 0.f, 0.f, 0.f, 0.f, 0.f, 0.f, 0.f};
  float acc2[8] = {0.f, 0.f, 0.f, 0.f, 0.f, 0.f, 0.f, 0.f};

  if (end > beg) {
    const int e1 = end - 1;
    int2 sA = srcw[min(beg + g, e1)];
    int2 sB = srcw[min(beg + 16 + g, e1)];
    for (int j = beg; j < end; j += 32) {
      const float wA = (j + g < end)      ? __int_as_float(sA.y) : 0.f;
      const float wB = (j + 16 + g < end) ? __int_as_float(sB.y) : 0.f;
      const uint4 vA = h1aq[(size_t)(unsigned)sA.x * 4 + fl];
      const uint4 vB = h1aq[(size_t)(unsigned)sB.x * 4 + fl];
      uint4 cA = make_uint4(0, 0, 0, 0), cB = make_uint4(0, 0, 0, 0);
      if (fl == 0) {
        cA = h1cq[(unsigned)sA.x];
        cB = h1cq[(unsigned)sB.x];
      }
      const int jn = j + 32;
      if (jn < end) {
        sA = srcw[min(jn + g, e1)];
        sB = srcw[min(jn + 16 + g, e1)];
      }
      ACC8(acc, vA, wA)
      ACC8(acc, vB, wB)
      if (fl == 0) {
        ACC8(acc2, cA, wA)
        ACC8(acc2, cB, wB)
      }
    }
  }

#pragma unroll
  for (int i = 0; i < 8; ++i) {
    acc[i]  += __shfl_xor(acc[i], 4);
    acc[i]  += __shfl_xor(acc[i], 8);
    acc[i]  += __shfl_xor(acc[i], 16);
    acc[i]  += __shfl_xor(acc[i], 32);
    acc2[i] += __shfl_xor(acc2[i], 4);
    acc2[i] += __shfl_xor(acc2[i], 8);
    acc2[i] += __shfl_xor(acc2[i], 16);
    acc2[i] += __shfl_xor(acc2[i], 32);
    acc2[i] += __shfl_xor(acc2[i], 1);
    acc2[i] += __shfl_xor(acc2[i], 2);
  }

  const int f0 = fl * 8;
  float m = -INFINITY;
#pragma unroll
  for (int i = 0; i < 8; ++i) {
    acc[i]  += b1[f0 + i];
    acc2[i] += b1[32 + i];
    m = fmaxf(m, acc[i]);
    m = fmaxf(m, acc2[i]);
  }
  m = fmaxf(m, __shfl_xor(m, 1));
  m = fmaxf(m, __shfl_xor(m, 2));

  float s = 0.f;
#pragma unroll
  for (int i = 0; i < 8; ++i) s += expf(acc[i] - m);
  s += __shfl_xor(s, 1);
  s += __shfl_xor(s, 2);
  float s2 = 0.f;
#pragma unroll
  for (int i = 0; i < 8; ++i) s2 += expf(acc2[i] - m);
  s += s2;

  const float lse = m + logf(s);
  if (lane < 4) {
    float* op = out + (size_t)node * OUT_FEATS + fl * 8;
    *(float4*)op       = make_float4(acc[0] - lse, acc[1] - lse,
                                     acc[2] - lse, acc[3] - lse);
    *(float4*)(op + 4) = make_float4(acc[4] - lse, acc[5] - lse,
                                     acc[6] - lse, acc[7] - lse);
  } else if (lane == 4) {
    float* op = out + (size_t)node * OUT_FEATS + 32;
    *(float4*)op       = make_float4(acc2[0] - lse, acc2[1] - lse,
                                     acc2[2] - lse, acc2[3] - lse);
    *(float4*)(op + 4) = make_float4(acc2[4] - lse, acc2[5] - lse,
                                     acc2[6] - lse, acc2[7] - lse);
  }
}

// ---------------------------------------------------------------------------
extern "C" void kernel_launch(void* const* d_in, const int* in_sizes, int n_in,
                              void* d_out, int out_size, void* d_ws, size_t ws_size,
                              hipStream_t stream) {
  const float* x   = (const float*)d_in[0];
  const float* W0  = (const float*)d_in[1];
  const float* b0  = (const float*)d_in[2];
  const float* W1  = (const float*)d_in[3];
  const float* b1  = (const float*)d_in[4];
  const float* ew  = (const float*)d_in[5];
  const int*   src = (const int*)d_in[6];
  const int*   dst = (const int*)d_in[7];
  float* out = (float*)d_out;

  // Workspace layout, peak ~85.6 MB (ws >= 102.4 MB):
  //   h0b2     [0,          25,600,000)   N*128 bf16
  //   srcw     [25,600,000, 51,200,000)   E int2, dst-sorted
  //   bucketed [51,200,000, 76,800,000)   E uint2, bucket-partitioned
  //   offsets  [76,800,000, 77,200,064)   N+1 int
  //   histG    [77,200,064, 77,506,624)   NB*NBLK int
  //   h1a      [77,506,624, 83,906,624)   N*32 bf16 (64 B rows, feats 0-31)
  //   h1c      [83,906,624, 85,506,624)   N*8  bf16 (16 B rows, feats 32-39)
  //   w1f      [85,506,624, 85,518,912)   768 uint4 (pre-swizzled W1 B-frags)
  //   w0f      [85,518,912, 85,584,448)   4096 uint4 (pre-swizzled W0 B-frags)
  //   bsum     [85,584,448, 85,585,232)   NB int (per-bucket edge totals)
  char* ws = (char*)d_ws;
  unsigned int* h0b2 = (unsigned int*)(ws);
  int2*  srcw     = (int2*)(ws + 25600000);
  uint2* bucketed = (uint2*)(ws + 51200000);
  int*   offsets  = (int*)(ws + 76800000);
  int*   histG    = (int*)(ws + 77200064);
  unsigned short* h1a = (unsigned short*)(ws + 77506624);
  unsigned short* h1c = (unsigned short*)(ws + 83906624);
  uint4* w1f      = (uint4*)(ws + 85506624);
  uint4* w0f      = (uint4*)(ws + 85518912);
  int*   bsum     = (int*)(ws + 85584448);

  hipMemsetAsync(bsum, 0, NB * sizeof(int), stream);
  p1hist_kernel<<<NBLK + 9, 256, 0, stream>>>(dst, histG, W1, w1f, W0, w0f, bsum);
  bscan_gemm0_kernel<<<NB + G0BLKS, 256, 0, stream>>>(
      bsum, histG, x, w0f, (unsigned short*)h0b2);
  p1scatter_kernel<<<NBLK, 256, 0, stream>>>(src, dst, ew, histG, bucketed);
  p2place_kernel<<<NB, 256, 0, stream>>>(bucketed, histG, offsets, srcw);

  gather0_gemm1_kernel<<<N_NODES / 4, 256, 0, stream>>>(
      (const uint4*)h0b2, srcw, offsets, b0, (const uint4*)w1f, h1a, h1c);
  gather1_lsm_kernel<<<N_NODES / 4, 256, 0, stream>>>(
      (const uint4*)h1a, (const uint4*)h1c, srcw, offsets, b1, out);
}